// Round 3
// baseline (796.021 us; speedup 1.0000x reference)
//
#include <hip/hip_runtime.h>

#define BSZ 16
#define NN 1024
#define FE 64
#define HD 128
#define NIT 4
#define TI 16

typedef unsigned short u16;
typedef __attribute__((ext_vector_type(8))) short bf16x8;
typedef __attribute__((ext_vector_type(4))) float f32x4;

__device__ __forceinline__ float4 ld4(const float* p) { return *(const float4*)p; }

__device__ __forceinline__ u16 f2bf_rne(float x) {
    unsigned int u = __float_as_uint(x);
    u += 0x7fffu + ((u >> 16) & 1u);
    return (u16)(u >> 16);
}
__device__ __forceinline__ float bf2f(u16 h) {
    return __uint_as_float(((unsigned int)h) << 16);
}

// ---------------- row-MLP: out[row,:] = relu( [in1(,in2)] @ W + b ) ----------------
template<int K, bool CONCAT2>
__global__ __launch_bounds__(128) void k_rowmlp(const float* __restrict__ in1,
                                                const float* __restrict__ in2,
                                                const float* __restrict__ W,
                                                const float* __restrict__ bias,
                                                float* __restrict__ out)
{
    __shared__ float Ws[K * HD];
    __shared__ float hsb[64 * K];
    const int t = threadIdx.x;
    const int row0 = blockIdx.x * 64;
    const int rg = t >> 4;
    const int dg = t & 15;
    const int r0 = rg * 8, d0 = dg * 8;

    float acc[8][8];
#pragma unroll
    for (int u = 0; u < 8; ++u)
#pragma unroll
        for (int v = 0; v < 8; ++v) acc[u][v] = 0.f;

    const int NPH = CONCAT2 ? 2 : 1;
    for (int ph = 0; ph < NPH; ++ph) {
        const float* src = ph ? in2 : in1;
        const float* Wp  = W + (size_t)ph * K * HD;
        if (ph) __syncthreads();
        for (int c = t; c < K * 32; c += 128)
            *(float4*)&Ws[c * 4] = ld4(&Wp[(size_t)c * 4]);
        for (int c = t; c < K * 16; c += 128) {
            int r = c / (K / 4);
            int g = c % (K / 4);
            float4 v = ld4(&src[(size_t)(row0 + r) * K + g * 4]);
            int gs = g ^ ((r >> 3) & 7);
            *(float4*)&hsb[r * K + gs * 4] = v;
        }
        __syncthreads();
        for (int k = 0; k < K; k += 4) {
            float4 hv[8];
#pragma unroll
            for (int u = 0; u < 8; ++u) {
                int gs = (k >> 2) ^ (((r0 + u) >> 3) & 7);
                hv[u] = ld4(&hsb[(r0 + u) * K + gs * 4]);
            }
#pragma unroll
            for (int kk = 0; kk < 4; ++kk) {
                float4 wa = ld4(&Ws[(k + kk) * HD + d0]);
                float4 wb = ld4(&Ws[(k + kk) * HD + d0 + 4]);
#pragma unroll
                for (int u = 0; u < 8; ++u) {
                    float hval = ((const float*)&hv[u])[kk];
                    acc[u][0] = fmaf(hval, wa.x, acc[u][0]);
                    acc[u][1] = fmaf(hval, wa.y, acc[u][1]);
                    acc[u][2] = fmaf(hval, wa.z, acc[u][2]);
                    acc[u][3] = fmaf(hval, wa.w, acc[u][3]);
                    acc[u][4] = fmaf(hval, wb.x, acc[u][4]);
                    acc[u][5] = fmaf(hval, wb.y, acc[u][5]);
                    acc[u][6] = fmaf(hval, wb.z, acc[u][6]);
                    acc[u][7] = fmaf(hval, wb.w, acc[u][7]);
                }
            }
        }
    }
    float b0[8];
#pragma unroll
    for (int v = 0; v < 8; ++v) b0[v] = bias[d0 + v];
#pragma unroll
    for (int u = 0; u < 8; ++u) {
        float4 o0, o1;
        o0.x = fmaxf(acc[u][0] + b0[0], 0.f);
        o0.y = fmaxf(acc[u][1] + b0[1], 0.f);
        o0.z = fmaxf(acc[u][2] + b0[2], 0.f);
        o0.w = fmaxf(acc[u][3] + b0[3], 0.f);
        o1.x = fmaxf(acc[u][4] + b0[4], 0.f);
        o1.y = fmaxf(acc[u][5] + b0[5], 0.f);
        o1.z = fmaxf(acc[u][6] + b0[6], 0.f);
        o1.w = fmaxf(acc[u][7] + b0[7], 0.f);
        float* op = &out[(size_t)(row0 + r0 + u) * HD + d0];
        *(float4*)op = o0;
        *(float4*)(op + 4) = o1;
    }
}

// -------------- split h (fp32) -> [hi | lo] bf16, K=256 per row --------------
__global__ __launch_bounds__(256) void k_split(const float* __restrict__ h,
                                               u16* __restrict__ hs)
{
    int i = blockIdx.x * 256 + threadIdx.x;
    float4 v = ld4(&h[(size_t)i * 4]);
    size_t row = (size_t)(i >> 5);
    int d = (i & 31) * 4;
    u16 hi[4], lo[4];
    float xs[4] = {v.x, v.y, v.z, v.w};
#pragma unroll
    for (int k = 0; k < 4; ++k) {
        hi[k] = f2bf_rne(xs[k]);
        lo[k] = f2bf_rne(xs[k] - bf2f(hi[k]));
    }
    uint2 uh, ul;
    uh.x = (unsigned)hi[0] | ((unsigned)hi[1] << 16);
    uh.y = (unsigned)hi[2] | ((unsigned)hi[3] << 16);
    ul.x = (unsigned)lo[0] | ((unsigned)lo[1] << 16);
    ul.y = (unsigned)lo[2] | ((unsigned)lo[3] << 16);
    *(uint2*)&hs[row * 256 + d]       = uh;
    *(uint2*)&hs[row * 256 + 128 + d] = ul;
}

// -------------- split+transpose msg (fp32 [k][d]) -> msgT bf16 [b][2][d][k] --------------
__global__ __launch_bounds__(256) void k_splitT(const float* __restrict__ msg,
                                                u16* __restrict__ msgT)
{
    __shared__ u16 Th[128 * 68];
    __shared__ u16 Tl[128 * 68];
    const int t = threadIdx.x;
    const int b = blockIdx.x & 15;
    const int k0 = (blockIdx.x >> 4) * 64;

    for (int c = t; c < 2048; c += 256) {
        int r = c >> 5;
        int d = (c & 31) * 4;
        float4 v = ld4(&msg[((size_t)b * NN + k0 + r) * HD + d]);
        float xs[4] = {v.x, v.y, v.z, v.w};
#pragma unroll
        for (int i2 = 0; i2 < 4; ++i2) {
            u16 hi = f2bf_rne(xs[i2]);
            u16 lo = f2bf_rne(xs[i2] - bf2f(hi));
            Th[(d + i2) * 68 + r] = hi;
            Tl[(d + i2) * 68 + r] = lo;
        }
    }
    __syncthreads();

    for (int c = t; c < 1024; c += 256) {
        int d = c >> 3;
        int kq = (c & 7) * 8;
        uint4 vh, vl;
        vh.x = *(const uint*)&Th[d * 68 + kq + 0];
        vh.y = *(const uint*)&Th[d * 68 + kq + 2];
        vh.z = *(const uint*)&Th[d * 68 + kq + 4];
        vh.w = *(const uint*)&Th[d * 68 + kq + 6];
        vl.x = *(const uint*)&Tl[d * 68 + kq + 0];
        vl.y = *(const uint*)&Tl[d * 68 + kq + 2];
        vl.z = *(const uint*)&Tl[d * 68 + kq + 4];
        vl.w = *(const uint*)&Tl[d * 68 + kq + 6];
        size_t obase = (size_t)b * 2 * 128 * 1024 + (size_t)d * 1024 + k0 + kq;
        *(uint4*)&msgT[obase]              = vh;
        *(uint4*)&msgT[obase + 128 * 1024] = vl;
    }
}

// -------------- fused m = softmax(A)@msg, A never materialized --------------
// GEN=0: A = |i-j|+1 formula. GEN=1: A = h_prev.h_prev^T/sqrt(128) from hsplit.
template<int GEN>
__global__ __launch_bounds__(512) void k_flash(const u16* __restrict__ hsplit,
                                               const u16* __restrict__ msgT,
                                               float* __restrict__ mout)
{
    __shared__ float S[TI][1028];     // logits, fp32
    __shared__ u16 Phi[TI][1024];     // P bf16 hi, granule-swizzled
    __shared__ u16 Plo[TI][1024];     // P bf16 lo
    __shared__ float inv_s[TI];

    const int t = threadIdx.x;
    const int wave = t >> 6, lane = t & 63;
    const int b = blockIdx.x & 15;            // batch fast -> same batch same XCD
    const int i0 = (blockIdx.x >> 4) * TI;
    const int lg = lane >> 4;                 // 0..3
    const int lc = lane & 15;                 // 0..15

    // ---- phase 1: logits S[q][j] ----
    if (GEN == 1) {
        const u16* hb = hsplit + (size_t)b * NN * 256;
        bf16x8 qf[8];
        const u16* qrow = hb + (size_t)(i0 + lc) * 256 + lg * 8;
#pragma unroll
        for (int c = 0; c < 8; ++c) qf[c] = *(const bf16x8*)(qrow + c * 32);

        const int j0 = wave * 128;
        const float scale = 0.08838834764831845f;
#pragma unroll
        for (int n = 0; n < 8; ++n) {
            f32x4 acc = (f32x4){0.f, 0.f, 0.f, 0.f};
            const u16* krow = hb + (size_t)(j0 + n * 16 + lc) * 256 + lg * 8;
#pragma unroll
            for (int c = 0; c < 8; ++c) {
                bf16x8 kf = *(const bf16x8*)(krow + c * 32);
                acc = __builtin_amdgcn_mfma_f32_16x16x32_bf16(qf[c], kf, acc, 0, 0, 0);
            }
            int j = j0 + n * 16 + lc;
#pragma unroll
            for (int r = 0; r < 4; ++r)
                S[lg * 4 + r][j] = acc[r] * scale;
        }
    } else {
        for (int idx = t; idx < TI * 1024; idx += 512) {
            int r = idx >> 10, j = idx & 1023;
            int di = i0 + r - j;
            S[r][j] = (float)(di < 0 ? -di : di) + 1.0f;
        }
    }
    __syncthreads();

    // ---- phase 2: softmax rows; write P as bf16 hi/lo (swizzled) ----
    for (int rr = 0; rr < 2; ++rr) {
        int r = wave * 2 + rr;
        float pv[16];
#pragma unroll
        for (int jj = 0; jj < 16; ++jj) pv[jj] = S[r][lane + 64 * jj];
        float mx = pv[0];
#pragma unroll
        for (int jj = 1; jj < 16; ++jj) mx = fmaxf(mx, pv[jj]);
#pragma unroll
        for (int off = 32; off > 0; off >>= 1) mx = fmaxf(mx, __shfl_down(mx, off));
        mx = __shfl(mx, 0);
        float s = 0.f;
#pragma unroll
        for (int jj = 0; jj < 16; ++jj) {
            float e = __expf(pv[jj] - mx);
            s += e;
            int j = lane + 64 * jj;
            int gs = ((j >> 3) ^ (r & 7)) * 8 + (j & 7);
            u16 hi = f2bf_rne(e);
            Phi[r][gs] = hi;
            Plo[r][gs] = f2bf_rne(e - bf2f(hi));
        }
#pragma unroll
        for (int off = 32; off > 0; off >>= 1) s += __shfl_down(s, off);
        if (lane == 0) inv_s[r] = 1.0f / s;
    }
    __syncthreads();

    // ---- phase 3: PV via MFMA, 3-term split; wave owns d-range 16 ----
    const int d0 = wave * 16;
    const u16* Mhi = msgT + (size_t)b * 2 * 128 * 1024 + (size_t)(d0 + lc) * 1024 + lg * 8;
    const u16* Mlo = Mhi + 128 * 1024;

    f32x4 macc = (f32x4){0.f, 0.f, 0.f, 0.f};
    const int rsw = lc & 7;
#pragma unroll 4
    for (int ks = 0; ks < 32; ++ks) {
        int gs = ((ks * 4 + lg) ^ rsw) * 8;
        bf16x8 bh = *(const bf16x8*)(Mhi + ks * 32);
        bf16x8 ah = *(const bf16x8*)&Phi[lc][gs];
        bf16x8 al = *(const bf16x8*)&Plo[lc][gs];
        macc = __builtin_amdgcn_mfma_f32_16x16x32_bf16(ah, bh, macc, 0, 0, 0);
        macc = __builtin_amdgcn_mfma_f32_16x16x32_bf16(al, bh, macc, 0, 0, 0);
    }
#pragma unroll 4
    for (int ks = 0; ks < 32; ++ks) {
        int gs = ((ks * 4 + lg) ^ rsw) * 8;
        bf16x8 bl = *(const bf16x8*)(Mlo + ks * 32);
        bf16x8 ah = *(const bf16x8*)&Phi[lc][gs];
        macc = __builtin_amdgcn_mfma_f32_16x16x32_bf16(ah, bl, macc, 0, 0, 0);
    }

    // ---- epilogue ----
#pragma unroll
    for (int r = 0; r < 4; ++r) {
        int q = lg * 4 + r;
        mout[((size_t)b * NN + i0 + q) * HD + d0 + lc] = macc[r] * inv_s[q];
    }
}

// -------------- A = h @ h^T / sqrt(128) via bf16 MFMA on [hi|lo] (K=256) --------------
__global__ __launch_bounds__(256) void k_anew_mfma(const u16* __restrict__ hs,
                                                   float* __restrict__ A)
{
    __shared__ u16 sa[128 * 64];
    __shared__ u16 sb[128 * 64];
    const int t = threadIdx.x;
    const int wave = t >> 6, lane = t & 63;
    const int b = blockIdx.z;
    const int i0 = blockIdx.y * 128;
    const int j0 = blockIdx.x * 128;
    const u16* hb = hs + (size_t)b * NN * 256;

    const int wr = wave >> 1, wc = wave & 1;

    f32x4 acc[4][4];
#pragma unroll
    for (int m = 0; m < 4; ++m)
#pragma unroll
        for (int n = 0; n < 4; ++n) acc[m][n] = (f32x4){0.f, 0.f, 0.f, 0.f};

    const int ch_r[4] = { (0 * 256 + t) >> 3, (1 * 256 + t) >> 3,
                          (2 * 256 + t) >> 3, (3 * 256 + t) >> 3 };
    const int ch_c = t & 7;

#define STAGE(step)                                                            \
    {                                                                          \
        uint4 va[4], vb[4];                                                    \
        _Pragma("unroll")                                                      \
        for (int s = 0; s < 4; ++s) {                                          \
            int r = ch_r[s];                                                   \
            const u16* ga = hb + (size_t)(i0 + r) * 256 + (step) * 64 + ch_c * 8; \
            const u16* gb = hb + (size_t)(j0 + r) * 256 + (step) * 64 + ch_c * 8; \
            va[s] = *(const uint4*)ga;                                         \
            vb[s] = *(const uint4*)gb;                                         \
        }                                                                      \
        _Pragma("unroll")                                                      \
        for (int s = 0; s < 4; ++s) {                                          \
            int r = ch_r[s];                                                   \
            int swz = (ch_c ^ (r & 7)) * 8;                                    \
            *(uint4*)&sa[r * 64 + swz] = va[s];                                \
            *(uint4*)&sb[r * 64 + swz] = vb[s];                                \
        }                                                                      \
    }

    STAGE(0);
    __syncthreads();

    for (int step = 0; step < 4; ++step) {
#pragma unroll
        for (int ks = 0; ks < 2; ++ks) {
            const int chunk = ks * 4 + (lane >> 4);
            bf16x8 af[4], bfr[4];
#pragma unroll
            for (int m = 0; m < 4; ++m) {
                int row = wr * 64 + m * 16 + (lane & 15);
                af[m] = *(const bf16x8*)&sa[row * 64 + ((chunk ^ (row & 7)) * 8)];
            }
#pragma unroll
            for (int n = 0; n < 4; ++n) {
                int row = wc * 64 + n * 16 + (lane & 15);
                bfr[n] = *(const bf16x8*)&sb[row * 64 + ((chunk ^ (row & 7)) * 8)];
            }
#pragma unroll
            for (int m = 0; m < 4; ++m)
#pragma unroll
                for (int n = 0; n < 4; ++n)
                    acc[m][n] = __builtin_amdgcn_mfma_f32_16x16x32_bf16(
                        af[m], bfr[n], acc[m][n], 0, 0, 0);
        }
        if (step < 3) {
            __syncthreads();
            STAGE(step + 1);
            __syncthreads();
        }
    }
#undef STAGE

    const float scale = 0.08838834764831845f;
#pragma unroll
    for (int m = 0; m < 4; ++m) {
        int col = i0 + wr * 64 + m * 16 + (lane >> 4) * 4;
#pragma unroll
        for (int n = 0; n < 4; ++n) {
            int row = j0 + wc * 64 + n * 16 + (lane & 15);
            float4 o;
            o.x = acc[m][n][0] * scale;
            o.y = acc[m][n][1] * scale;
            o.z = acc[m][n][2] * scale;
            o.w = acc[m][n][3] * scale;
            *(float4*)&A[((size_t)b * NN + row) * NN + col] = o;
        }
    }
}

extern "C" void kernel_launch(void* const* d_in, const int* in_sizes, int n_in,
                              void* d_out, int out_size, void* d_ws, size_t ws_size,
                              hipStream_t stream)
{
    const float* x   = (const float*)d_in[0];
    const float* We0 = (const float*)d_in[1];
    const float* be0 = (const float*)d_in[2];
    const float* We1 = (const float*)d_in[3];
    const float* be1 = (const float*)d_in[4];
    const float* Wm  = (const float*)d_in[5];
    const float* bm  = (const float*)d_in[6];
    const float* Wu  = (const float*)d_in[7];
    const float* bu  = (const float*)d_in[8];
    float* out = (float*)d_out;

    char* ws = (char*)d_ws;
    const size_t SZ = (size_t)BSZ * NN * HD * 4;   // 8 MB
    float* h      = (float*)(ws);
    float* msg    = (float*)(ws + SZ);
    float* m      = (float*)(ws + 2 * SZ);
    u16*   hsplit = (u16*)(ws + 3 * SZ);           // 16x1024x256 bf16 = 8 MB
    u16*   msgT   = (u16*)(ws + 4 * SZ);           // 16x2x128x1024 bf16 = 8 MB

    const int nrow_blocks = BSZ * NN / 64;         // 256
    const int nsplit_blocks = BSZ * NN * HD / 4 / 256;  // 2048

    // embedding MLP
    k_rowmlp<FE, false><<<nrow_blocks, 128, 0, stream>>>(x, nullptr, We0, be0, h);
    k_rowmlp<HD, false><<<nrow_blocks, 128, 0, stream>>>(h, nullptr, We1, be1, h);

    for (int k = 0; k < NIT; ++k) {
        // msg = relu(h @ Wm[k] + bm[k])
        k_rowmlp<HD, false><<<nrow_blocks, 128, 0, stream>>>(
            h, nullptr, Wm + (size_t)k * HD * HD, bm + (size_t)k * HD, msg);
        // msgT = split+transpose(msg)
        k_splitT<<<256, 256, 0, stream>>>(msg, msgT);
        // m = softmax(A_prev) @ msg, fused (A never materialized)
        if (k == 0)
            k_flash<0><<<BSZ * 64, 512, 0, stream>>>(hsplit, msgT, m);
        else
            k_flash<1><<<BSZ * 64, 512, 0, stream>>>(hsplit, msgT, m);
        // h = relu(concat([h, m]) @ Wu[k] + bu[k])   (in-place, row-local)
        k_rowmlp<HD, true><<<nrow_blocks, 128, 0, stream>>>(
            h, m, Wu + (size_t)k * 2 * HD * HD, bu + (size_t)k * HD, h);
        // hsplit = [bf16_hi(h) | bf16_lo(h)]  (feeds next iter's flash / final A)
        k_split<<<nsplit_blocks, 256, 0, stream>>>(h, hsplit);
    }
    // final A = h @ h^T / sqrt(128)
    k_anew_mfma<<<dim3(NN / 128, NN / 128, BSZ), 256, 0, stream>>>(hsplit, out);
}

// Round 4
// 518.293 us; speedup vs baseline: 1.5359x; 1.5359x over previous
//
#include <hip/hip_runtime.h>

#define BSZ 16
#define NN 1024
#define FE 64
#define HD 128
#define NIT 4
#define TI 16

typedef unsigned short u16;
typedef __attribute__((ext_vector_type(8))) short bf16x8;
typedef __attribute__((ext_vector_type(4))) float f32x4;

__device__ __forceinline__ float4 ld4(const float* p) { return *(const float4*)p; }

__device__ __forceinline__ u16 f2bf_rne(float x) {
    unsigned int u = __float_as_uint(x);
    u += 0x7fffu + ((u >> 16) & 1u);
    return (u16)(u >> 16);
}
__device__ __forceinline__ float bf2f(u16 h) {
    return __uint_as_float(((unsigned int)h) << 16);
}

// ---------------- row-MLP: out[row,:] = relu( [in1(,in2)] @ W + b ) ----------------
// 64 rows/block, 256 threads, 4x8 per thread. W read from global (L1 broadcast),
// rows staged in LDS (32 KB max -> 5 blocks/CU, 20 waves/CU).
template<int K, bool CONCAT2>
__global__ __launch_bounds__(256) void k_rowmlp(const float* __restrict__ in1,
                                                const float* __restrict__ in2,
                                                const float* __restrict__ W,
                                                const float* __restrict__ bias,
                                                float* __restrict__ out)
{
    __shared__ float hsb[64 * K];
    const int t = threadIdx.x;
    const int row0 = blockIdx.x * 64;
    const int rg = t >> 4;            // 0..15 -> rows rg*4..+3
    const int dg = t & 15;            // d cols dg*8..+8
    const int r0 = rg * 4, d0 = dg * 8;
    const int shv = rg & 7;           // row-swizzle for this thread's 4 rows

    float acc[4][8];
#pragma unroll
    for (int u = 0; u < 4; ++u)
#pragma unroll
        for (int v = 0; v < 8; ++v) acc[u][v] = 0.f;

    const int NPH = CONCAT2 ? 2 : 1;
    for (int ph = 0; ph < NPH; ++ph) {
        const float* src = ph ? in2 : in1;
        const float* Wp  = W + (size_t)ph * K * HD;
        if (ph) __syncthreads();
        // stage 64 input rows, swizzled: granule g -> g ^ ((r>>2)&7)
        for (int c = t; c < K * 16; c += 256) {
            int r = c / (K / 4);
            int g = c % (K / 4);
            float4 v = ld4(&src[(size_t)(row0 + r) * K + g * 4]);
            int gs = g ^ ((r >> 2) & 7);
            *(float4*)&hsb[r * K + gs * 4] = v;
        }
        __syncthreads();
        for (int k = 0; k < K; k += 4) {
            float4 hv[4];
            const int gk = ((k >> 2) ^ shv) * 4;
#pragma unroll
            for (int u = 0; u < 4; ++u)
                hv[u] = ld4(&hsb[(r0 + u) * K + gk]);
#pragma unroll
            for (int kk = 0; kk < 4; ++kk) {
                float4 wa = ld4(&Wp[(size_t)(k + kk) * HD + d0]);
                float4 wb = ld4(&Wp[(size_t)(k + kk) * HD + d0 + 4]);
#pragma unroll
                for (int u = 0; u < 4; ++u) {
                    float hval = ((const float*)&hv[u])[kk];
                    acc[u][0] = fmaf(hval, wa.x, acc[u][0]);
                    acc[u][1] = fmaf(hval, wa.y, acc[u][1]);
                    acc[u][2] = fmaf(hval, wa.z, acc[u][2]);
                    acc[u][3] = fmaf(hval, wa.w, acc[u][3]);
                    acc[u][4] = fmaf(hval, wb.x, acc[u][4]);
                    acc[u][5] = fmaf(hval, wb.y, acc[u][5]);
                    acc[u][6] = fmaf(hval, wb.z, acc[u][6]);
                    acc[u][7] = fmaf(hval, wb.w, acc[u][7]);
                }
            }
        }
    }
    float b0[8];
#pragma unroll
    for (int v = 0; v < 8; ++v) b0[v] = bias[d0 + v];
#pragma unroll
    for (int u = 0; u < 4; ++u) {
        float4 o0, o1;
        o0.x = fmaxf(acc[u][0] + b0[0], 0.f);
        o0.y = fmaxf(acc[u][1] + b0[1], 0.f);
        o0.z = fmaxf(acc[u][2] + b0[2], 0.f);
        o0.w = fmaxf(acc[u][3] + b0[3], 0.f);
        o1.x = fmaxf(acc[u][4] + b0[4], 0.f);
        o1.y = fmaxf(acc[u][5] + b0[5], 0.f);
        o1.z = fmaxf(acc[u][6] + b0[6], 0.f);
        o1.w = fmaxf(acc[u][7] + b0[7], 0.f);
        float* op = &out[(size_t)(row0 + r0 + u) * HD + d0];
        *(float4*)op = o0;
        *(float4*)(op + 4) = o1;
    }
}

// -------------- transpose msg (fp32 [k][d]) -> msgT bf16 [b][d][k] --------------
__global__ __launch_bounds__(256) void k_transp(const float* __restrict__ msg,
                                                u16* __restrict__ msgT)
{
    __shared__ u16 Th[128 * 68];
    const int t = threadIdx.x;
    const int b = blockIdx.x & 15;
    const int k0 = (blockIdx.x >> 4) * 64;

    for (int c = t; c < 2048; c += 256) {
        int r = c >> 5;
        int d = (c & 31) * 4;
        float4 v = ld4(&msg[((size_t)b * NN + k0 + r) * HD + d]);
        float xs[4] = {v.x, v.y, v.z, v.w};
#pragma unroll
        for (int i2 = 0; i2 < 4; ++i2)
            Th[(d + i2) * 68 + r] = f2bf_rne(xs[i2]);
    }
    __syncthreads();

    for (int c = t; c < 1024; c += 256) {
        int d = c >> 3;
        int kq = (c & 7) * 8;
        uint4 vh;
        vh.x = *(const uint*)&Th[d * 68 + kq + 0];
        vh.y = *(const uint*)&Th[d * 68 + kq + 2];
        vh.z = *(const uint*)&Th[d * 68 + kq + 4];
        vh.w = *(const uint*)&Th[d * 68 + kq + 6];
        *(uint4*)&msgT[(size_t)b * HD * NN + (size_t)d * NN + k0 + kq] = vh;
    }
}

// -------------- m = softmax(A) @ msg : fp32 softmax + bf16 MFMA PV --------------
// GEN=0: A = |i-j|+1 formula (A not read). 16 q-rows/block, 256 thr, LDS 32 KB.
template<int GEN>
__global__ __launch_bounds__(256) void k_pv(const float* __restrict__ A,
                                            const u16* __restrict__ msgT,
                                            float* __restrict__ mout)
{
    __shared__ u16 Pb[TI][1024];      // P bf16, granule-swizzled
    __shared__ float inv_s[TI];
    const int t = threadIdx.x;
    const int wave = t >> 6, lane = t & 63;
    const int b = blockIdx.x >> 6;    // 64 consecutive blocks = same batch
    const int i0 = (blockIdx.x & 63) * TI;

    // ---- softmax: wave owns rows 4*wave..+3; A read straight from global ----
    for (int rr = 0; rr < 4; ++rr) {
        const int r = wave * 4 + rr;
        float pv[16];
        if (GEN == 0) {
            const int i = i0 + r;
#pragma unroll
            for (int q = 0; q < 4; ++q) {
                int jb = lane * 4 + 256 * q;
#pragma unroll
                for (int x = 0; x < 4; ++x) {
                    int di = i - (jb + x);
                    pv[q * 4 + x] = (float)(di < 0 ? -di : di) + 1.0f;
                }
            }
        } else {
            const float* Ar = A + ((size_t)b * NN + i0 + r) * NN;
#pragma unroll
            for (int q = 0; q < 4; ++q) {
                float4 v = ld4(&Ar[lane * 4 + 256 * q]);
                pv[q * 4 + 0] = v.x; pv[q * 4 + 1] = v.y;
                pv[q * 4 + 2] = v.z; pv[q * 4 + 3] = v.w;
            }
        }
        float mx = pv[0];
#pragma unroll
        for (int jj = 1; jj < 16; ++jj) mx = fmaxf(mx, pv[jj]);
#pragma unroll
        for (int off = 32; off > 0; off >>= 1) mx = fmaxf(mx, __shfl_down(mx, off));
        mx = __shfl(mx, 0);
        float s = 0.f;
#pragma unroll
        for (int q = 0; q < 4; ++q) {
            u16 e[4];
#pragma unroll
            for (int x = 0; x < 4; ++x) {
                float ev = __expf(pv[q * 4 + x] - mx);
                s += ev;
                e[x] = f2bf_rne(ev);
            }
            int jb = lane * 4 + 256 * q;
            uint2 w;
            w.x = (unsigned)e[0] | ((unsigned)e[1] << 16);
            w.y = (unsigned)e[2] | ((unsigned)e[3] << 16);
            *(uint2*)&Pb[r][((jb >> 3) ^ (r & 7)) * 8 + (jb & 7)] = w;
        }
#pragma unroll
        for (int off = 32; off > 0; off >>= 1) s += __shfl_down(s, off);
        if (lane == 0) inv_s[r] = 1.0f / s;
    }
    __syncthreads();

    // ---- PV via MFMA: wave owns d-range 32 (two 16-wide tiles) ----
    const int lg = lane >> 4, lc = lane & 15;
    const u16* M0 = msgT + (size_t)b * HD * NN + (size_t)(wave * 32 + lc) * NN + lg * 8;
    const u16* M1 = M0 + 16 * NN;
    f32x4 acc0 = (f32x4){0.f, 0.f, 0.f, 0.f};
    f32x4 acc1 = (f32x4){0.f, 0.f, 0.f, 0.f};
    const int rsw = lc & 7;
#pragma unroll 4
    for (int ks = 0; ks < 32; ++ks) {
        bf16x8 a  = *(const bf16x8*)&Pb[lc][((ks * 4 + lg) ^ rsw) * 8];
        bf16x8 b0 = *(const bf16x8*)(M0 + ks * 32);
        bf16x8 b1 = *(const bf16x8*)(M1 + ks * 32);
        acc0 = __builtin_amdgcn_mfma_f32_16x16x32_bf16(a, b0, acc0, 0, 0, 0);
        acc1 = __builtin_amdgcn_mfma_f32_16x16x32_bf16(a, b1, acc1, 0, 0, 0);
    }
#pragma unroll
    for (int r2 = 0; r2 < 4; ++r2) {
        int q = lg * 4 + r2;
        float is = inv_s[q];
        float* op = &mout[((size_t)b * NN + i0 + q) * HD + wave * 32 + lc];
        op[0]  = acc0[r2] * is;
        op[16] = acc1[r2] * is;
    }
}

// -------------- split h (fp32) -> [hi | lo] bf16, K=256 per row --------------
__global__ __launch_bounds__(256) void k_split(const float* __restrict__ h,
                                               u16* __restrict__ hs)
{
    int i = blockIdx.x * 256 + threadIdx.x;
    float4 v = ld4(&h[(size_t)i * 4]);
    size_t row = (size_t)(i >> 5);
    int d = (i & 31) * 4;
    u16 hi[4], lo[4];
    float xs[4] = {v.x, v.y, v.z, v.w};
#pragma unroll
    for (int k = 0; k < 4; ++k) {
        hi[k] = f2bf_rne(xs[k]);
        lo[k] = f2bf_rne(xs[k] - bf2f(hi[k]));
    }
    uint2 uh, ul;
    uh.x = (unsigned)hi[0] | ((unsigned)hi[1] << 16);
    uh.y = (unsigned)hi[2] | ((unsigned)hi[3] << 16);
    ul.x = (unsigned)lo[0] | ((unsigned)lo[1] << 16);
    ul.y = (unsigned)lo[2] | ((unsigned)lo[3] << 16);
    *(uint2*)&hs[row * 256 + d]       = uh;
    *(uint2*)&hs[row * 256 + 128 + d] = ul;
}

// -------------- A = h @ h^T / sqrt(128) via bf16 MFMA on [hi|lo] (K=256) --------------
__global__ __launch_bounds__(256) void k_anew_mfma(const u16* __restrict__ hs,
                                                   float* __restrict__ A)
{
    __shared__ u16 sa[128 * 64];
    __shared__ u16 sb[128 * 64];
    const int t = threadIdx.x;
    const int wave = t >> 6, lane = t & 63;
    const int b = blockIdx.z;
    const int i0 = blockIdx.y * 128;
    const int j0 = blockIdx.x * 128;
    const u16* hb = hs + (size_t)b * NN * 256;

    const int wr = wave >> 1, wc = wave & 1;

    f32x4 acc[4][4];
#pragma unroll
    for (int m = 0; m < 4; ++m)
#pragma unroll
        for (int n = 0; n < 4; ++n) acc[m][n] = (f32x4){0.f, 0.f, 0.f, 0.f};

    const int ch_r[4] = { (0 * 256 + t) >> 3, (1 * 256 + t) >> 3,
                          (2 * 256 + t) >> 3, (3 * 256 + t) >> 3 };
    const int ch_c = t & 7;

#define STAGE(step)                                                            \
    {                                                                          \
        uint4 va[4], vb[4];                                                    \
        _Pragma("unroll")                                                      \
        for (int s = 0; s < 4; ++s) {                                          \
            int r = ch_r[s];                                                   \
            const u16* ga = hb + (size_t)(i0 + r) * 256 + (step) * 64 + ch_c * 8; \
            const u16* gb = hb + (size_t)(j0 + r) * 256 + (step) * 64 + ch_c * 8; \
            va[s] = *(const uint4*)ga;                                         \
            vb[s] = *(const uint4*)gb;                                         \
        }                                                                      \
        _Pragma("unroll")                                                      \
        for (int s = 0; s < 4; ++s) {                                          \
            int r = ch_r[s];                                                   \
            int swz = (ch_c ^ (r & 7)) * 8;                                    \
            *(uint4*)&sa[r * 64 + swz] = va[s];                                \
            *(uint4*)&sb[r * 64 + swz] = vb[s];                                \
        }                                                                      \
    }

    STAGE(0);
    __syncthreads();

    for (int step = 0; step < 4; ++step) {
#pragma unroll
        for (int ks = 0; ks < 2; ++ks) {
            const int chunk = ks * 4 + (lane >> 4);
            bf16x8 af[4], bfr[4];
#pragma unroll
            for (int m = 0; m < 4; ++m) {
                int row = wr * 64 + m * 16 + (lane & 15);
                af[m] = *(const bf16x8*)&sa[row * 64 + ((chunk ^ (row & 7)) * 8)];
            }
#pragma unroll
            for (int n = 0; n < 4; ++n) {
                int row = wc * 64 + n * 16 + (lane & 15);
                bfr[n] = *(const bf16x8*)&sb[row * 64 + ((chunk ^ (row & 7)) * 8)];
            }
#pragma unroll
            for (int m = 0; m < 4; ++m)
#pragma unroll
                for (int n = 0; n < 4; ++n)
                    acc[m][n] = __builtin_amdgcn_mfma_f32_16x16x32_bf16(
                        af[m], bfr[n], acc[m][n], 0, 0, 0);
        }
        if (step < 3) {
            __syncthreads();
            STAGE(step + 1);
            __syncthreads();
        }
    }
#undef STAGE

    const float scale = 0.08838834764831845f;
#pragma unroll
    for (int m = 0; m < 4; ++m) {
        int col = i0 + wr * 64 + m * 16 + (lane >> 4) * 4;
#pragma unroll
        for (int n = 0; n < 4; ++n) {
            int row = j0 + wc * 64 + n * 16 + (lane & 15);
            float4 o;
            o.x = acc[m][n][0] * scale;
            o.y = acc[m][n][1] * scale;
            o.z = acc[m][n][2] * scale;
            o.w = acc[m][n][3] * scale;
            *(float4*)&A[((size_t)b * NN + row) * NN + col] = o;
        }
    }
}

extern "C" void kernel_launch(void* const* d_in, const int* in_sizes, int n_in,
                              void* d_out, int out_size, void* d_ws, size_t ws_size,
                              hipStream_t stream)
{
    const float* x   = (const float*)d_in[0];
    const float* We0 = (const float*)d_in[1];
    const float* be0 = (const float*)d_in[2];
    const float* We1 = (const float*)d_in[3];
    const float* be1 = (const float*)d_in[4];
    const float* Wm  = (const float*)d_in[5];
    const float* bm  = (const float*)d_in[6];
    const float* Wu  = (const float*)d_in[7];
    const float* bu  = (const float*)d_in[8];
    float* out = (float*)d_out;

    char* ws = (char*)d_ws;
    const size_t SZ = (size_t)BSZ * NN * HD * 4;   // 8 MB
    float* h      = (float*)(ws);
    float* msg    = (float*)(ws + SZ);
    float* m      = (float*)(ws + 2 * SZ);
    u16*   hsplit = (u16*)(ws + 3 * SZ);           // 8 MB
    u16*   msgT   = (u16*)(ws + 3 * SZ);           // shares region: disjoint lifetime
    float* A      = out;                           // intermediate A lives in d_out
                                                   // (fully rewritten each iter)

    const int nrow_blocks = BSZ * NN / 64;              // 256
    const int nsplit_blocks = BSZ * NN * HD / 4 / 256;  // 2048

    // embedding MLP
    k_rowmlp<FE, false><<<nrow_blocks, 256, 0, stream>>>(x, nullptr, We0, be0, h);
    k_rowmlp<HD, false><<<nrow_blocks, 256, 0, stream>>>(h, nullptr, We1, be1, h);

    for (int k = 0; k < NIT; ++k) {
        // msg = relu(h @ Wm[k] + bm[k])
        k_rowmlp<HD, false><<<nrow_blocks, 256, 0, stream>>>(
            h, nullptr, Wm + (size_t)k * HD * HD, bm + (size_t)k * HD, msg);
        // msgT = bf16 transpose of msg
        k_transp<<<256, 256, 0, stream>>>(msg, msgT);
        // m = softmax(A) @ msg
        if (k == 0)
            k_pv<0><<<BSZ * 64, 256, 0, stream>>>(A, msgT, m);
        else
            k_pv<1><<<BSZ * 64, 256, 0, stream>>>(A, msgT, m);
        // h = relu(concat([h, m]) @ Wu[k] + bu[k])   (in-place, row-local)
        k_rowmlp<HD, true><<<nrow_blocks, 256, 0, stream>>>(
            h, m, Wu + (size_t)k * 2 * HD * HD, bu + (size_t)k * HD, h);
        // hsplit = [bf16_hi(h) | bf16_lo(h)]  (overwrites msgT region - msgT dead)
        k_split<<<nsplit_blocks, 256, 0, stream>>>(h, hsplit);
        // A = h @ h^T / sqrt(128)  (last iteration: A == out)
        k_anew_mfma<<<dim3(NN / 128, NN / 128, BSZ), 256, 0, stream>>>(hsplit, A);
    }
}